// Round 7
// baseline (93.471 us; speedup 1.0000x reference)
//
#include <hip/hip_runtime.h>
#include <hip/hip_bf16.h>

// Gauss linking integral between kinematic-chain segment pairs, fully fused.
// motion1, motion2: (B=32, F=1024, J=22, 3) fp32. out (32,1023).
// R6: single kernel. Block = 256 thr = 2 halves x 8 frame-pairs x 16 i1
// -> computes 16 frames' gli in LDS, emits 15 vel outputs (grid strides 15).
// Packed float2 math throughout; rsq guard via pk_max(q, FLT_MIN).

#define NF 1024
#define NB 32
#define FOUT 15             // vel outputs per block
#define FCMP 16             // frames computed per block (8 float2 pairs)
#define JSTRIDE 18          // 16 frames + 2 pad (even -> b64-aligned float2)
#define RSTRIDE 81          // red frame stride (odd -> no kp bank collision)

typedef float v2f __attribute__((ext_vector_type(2)));

struct W3 { v2f x, y, z; };

__device__ __forceinline__ v2f FMA2(v2f a, v2f b, v2f c) {
    return __builtin_elementwise_fma(a, b, c);
}
__device__ __forceinline__ W3 wsub(W3 a, W3 b) { return {a.x-b.x, a.y-b.y, a.z-b.z}; }
__device__ __forceinline__ W3 wcross(W3 a, W3 b) {
    return { FMA2(a.y, b.z, -(a.z*b.y)),
             FMA2(a.z, b.x, -(a.x*b.z)),
             FMA2(a.x, b.y, -(a.y*b.x)) };
}
__device__ __forceinline__ v2f wdot(W3 a, W3 b) {
    return FMA2(a.x, b.x, FMA2(a.y, b.y, a.z*b.z));
}
// rsq with zero-norm guard folded into a flush floor: if a face is exactly
// degenerate its cross (and thus the dot numerator) is 0, so 0*rsq(FLT_MIN)=0
// reproduces the ref's where(norm>0,...,0) path.
__device__ __forceinline__ v2f rsq_floor(v2f q) {
    q = __builtin_elementwise_max(q, (v2f)(1.17549435e-38f));
    v2f r;
    r.x = __builtin_amdgcn_rsqf(q.x);
    r.y = __builtin_amdgcn_rsqf(q.y);
    return r;
}
__device__ __forceinline__ v2f clamp2(v2f v) {
    v = __builtin_elementwise_max(v, (v2f)(-1.0f + 1e-7f));
    v = __builtin_elementwise_min(v, (v2f)( 1.0f - 1e-7f));
    return v;
}
// asin via Abramowitz-Stegun 4.4.46 (7-term), packed polynomial. |err|<=2e-8.
__device__ __forceinline__ v2f asin2(v2f x) {
    v2f ax; ax.x = fabsf(x.x); ax.y = fabsf(x.y);
    v2f p = FMA2(ax, (v2f)(-0.0012624911f), (v2f)(0.0066700901f));
    p = FMA2(ax, p, (v2f)(-0.0170881256f));
    p = FMA2(ax, p, (v2f)( 0.0308918810f));
    p = FMA2(ax, p, (v2f)(-0.0501743046f));
    p = FMA2(ax, p, (v2f)( 0.0889789874f));
    p = FMA2(ax, p, (v2f)(-0.2145988016f));
    p = FMA2(ax, p, (v2f)( 1.5707963050f));
    v2f om = (v2f)(1.0f) - ax;
    v2f s; s.x = __builtin_amdgcn_sqrtf(om.x); s.y = __builtin_amdgcn_sqrtf(om.y);
    v2f r = FMA2(-s, p, (v2f)(1.57079632679f));
    r.x = copysignf(r.x, x.x);
    r.y = copysignf(r.y, x.y);
    return r;
}

// smem phases: [stage jT1|jT2: 2*66*18=2376] -> [red: 2*16*81=2592 | gliL: 400]
#define SMEM_FLOATS (2 * FCMP * RSTRIDE + FCMP * 25)   // 2992

__global__ __launch_bounds__(256)
void fused_kernel(const float* __restrict__ m1, const float* __restrict__ m2,
                  float* __restrict__ out)
{
    __shared__ float smem[SMEM_FLOATS];
    float* jT1 = smem;
    float* jT2 = smem + 66 * JSTRIDE;

    const int f0 = blockIdx.x * FOUT;
    const int b  = blockIdx.y;
    const int t  = threadIdx.x;

    // Stage FCMP frames transposed: jT[off][f] = m[min(f0+f,NF-1)][off].
    const size_t mbase = (size_t)b * NF * 66;
    for (int i = t; i < FCMP * 66; i += 256) {
        int f   = i / 66;
        int off = i - f * 66;
        int fidx = f0 + f; if (fidx > NF - 1) fidx = NF - 1;
        size_t ga = mbase + (size_t)fidx * 66 + off;
        jT1[off * JSTRIDE + f] = m1[ga];
        jT2[off * JSTRIDE + f] = m2[ga];
    }
    __syncthreads();

    constexpr int seg_a[16] = {2,5,8,  1,4,7,  3,6,9,12,  14,17,19,  13,16,18};
    constexpr int seg_b[16] = {5,8,11, 4,7,10, 6,9,12,15, 17,19,21,  16,18,20};
    constexpr int seg_p[16] = {0,0,0,  1,1,1,  2,2,2,2,   3,3,3,     4,4,4};

    const int half = t >> 7;         // which 8 i2's this thread owns
    const int kp   = (t >> 4) & 7;   // frame pair: local frames 2kp, 2kp+1
    const int i1   = t & 15;         // motion1 segment (p1 fixed per thread)
    const int fc   = 2 * kp;

    const int a1 = seg_a[i1] * 3, b1 = seg_b[i1] * 3;

    #define LD2(base, off) (*(const v2f*)&(base)[(off) * JSTRIDE + fc])
    W3 S1{LD2(jT1, a1), LD2(jT1, a1+1), LD2(jT1, a1+2)};
    W3 E1{LD2(jT1, b1), LD2(jT1, b1+1), LD2(jT1, b1+2)};
    W3 r12 = wsub(E1, S1);

    v2f acc[5] = {(v2f)(0.0f), (v2f)(0.0f), (v2f)(0.0f), (v2f)(0.0f), (v2f)(0.0f)};

    auto body = [&](int i2) {
        const int a2 = seg_a[i2] * 3, b2 = seg_b[i2] * 3;
        W3 S2{LD2(jT2, a2), LD2(jT2, a2+1), LD2(jT2, a2+2)};
        W3 E2{LD2(jT2, b2), LD2(jT2, b2+1), LD2(jT2, b2+2)};

        W3 r13 = wsub(S2, S1);
        W3 r14 = wsub(E2, S1);
        W3 r23 = wsub(S2, E1);
        W3 r24 = wsub(E2, E1);
        W3 r34 = wsub(E2, S2);

        W3 c0 = wcross(r13, r14);
        W3 c1 = wcross(r14, r24);
        W3 c2 = wcross(r24, r23);
        W3 c3 = wcross(r23, r13);

        v2f n0 = wdot(c0, c0), n1 = wdot(c1, c1);
        v2f n2 = wdot(c2, c2), n3 = wdot(c3, c3);

        v2f i01 = rsq_floor(n0 * n1);
        v2f i12 = rsq_floor(n1 * n2);
        v2f i23 = rsq_floor(n2 * n3);
        v2f i30 = rsq_floor(n3 * n0);

        v2f d0 = clamp2(wdot(c0, c1) * i01);
        v2f d1 = clamp2(wdot(c1, c2) * i12);
        v2f d2 = clamp2(wdot(c2, c3) * i23);
        v2f d3 = clamp2(wdot(c3, c0) * i30);

        v2f g = asin2(d0) + asin2(d1) + asin2(d2) + asin2(d3);

        v2f sgn = wdot(wcross(r34, r12), r13);
        g.x = (sgn.x <= 0.0f) ? -g.x : g.x;
        g.y = (sgn.y <= 0.0f) ? -g.y : g.y;

        acc[seg_p[i2]] += g;   // i2 compile-time after unroll -> folds
    };

    if (half == 0) {           // wave-uniform branch (t>>7)
#pragma unroll
        for (int i2 = 0; i2 < 8; ++i2) body(i2);
    } else {
#pragma unroll
        for (int i2 = 8; i2 < 16; ++i2) body(i2);
    }
    #undef LD2

    __syncthreads();   // staging dead; alias smem as red[2][FCMP][RSTRIDE]

    float* red  = smem;                       // [half][frame][i1*5+p]
    float* gliL = smem + 2 * FCMP * RSTRIDE;  // [frame][25]
#pragma unroll
    for (int p = 0; p < 5; ++p) {
        red[(half * FCMP + fc    ) * RSTRIDE + i1 * 5 + p] = acc[p].x * 0.07957747154594767f;
        red[(half * FCMP + fc + 1) * RSTRIDE + i1 * 5 + p] = acc[p].y * 0.07957747154594767f;
    }
    __syncthreads();

    // 400 items = FCMP frames x 25 bins; sum halves and i1 in path(p1).
    constexpr int grp_s[5] = {0, 3, 6, 10, 13};
    constexpr int grp_e[5] = {3, 6, 10, 13, 16};
    for (int item = t; item < FCMP * 25; item += 256) {
        int f   = item / 25;
        int bin = item - f * 25;
        int p1 = bin / 5, p2 = bin - p1 * 5;
        float s = 0.0f;
        for (int i = grp_s[p1]; i < grp_e[p1]; ++i)
            s += red[(f       ) * RSTRIDE + i * 5 + p2]
               + red[(f + FCMP) * RSTRIDE + i * 5 + p2];
        gliL[f * 25 + bin] = s;
    }
    __syncthreads();

    // vel: out[b, f0+k] = max_p |gliL[k+1][p] - gliL[k][p]|, k < FOUT
    if (t < FOUT) {
        int f = f0 + t;
        if (f < NF - 1) {
            const float* s0 = gliL + t * 25;
            float m = 0.0f;
#pragma unroll
            for (int p = 0; p < 25; ++p)
                m = fmaxf(m, fabsf(s0[p + 25] - s0[p]));
            out[(size_t)b * (NF - 1) + f] = m;
        }
    }
}

extern "C" void kernel_launch(void* const* d_in, const int* in_sizes, int n_in,
                              void* d_out, int out_size, void* d_ws, size_t ws_size,
                              hipStream_t stream)
{
    const float* m1 = (const float*)d_in[0];
    const float* m2 = (const float*)d_in[1];
    float* out = (float*)d_out;

    const int gx = (NF - 1 + FOUT - 1) / FOUT;   // 69
    hipLaunchKernelGGL(fused_kernel, dim3(gx, NB), dim3(256), 0, stream,
                       m1, m2, out);
}

// Round 9
// 91.078 us; speedup vs baseline: 1.0263x; 1.0263x over previous
//
#include <hip/hip_runtime.h>
#include <hip/hip_bf16.h>

// Gauss linking integral between kinematic-chain segment pairs.
// motion1, motion2: (B=32, F=1024, J=22, 3) fp32. out (32,1023).
// Final: R5 two-kernel structure (best measured) + R6 micro-opts.
// Block = 256 thr = 2 halves x 8 frame-pairs x 16 i1 -> 16 frames/block.
// Packed float2 (v_pk_*) math; 8 packed i2-iters/thread; no LDS atomics.

#define NF 1024
#define NB 32
#define FPB 16              // frames per block (8 float2 pairs)
#define JSTRIDE 18          // 16 frames + 2 pad (even -> b64-aligned float2)
#define RSTRIDE 81          // red frame stride (odd -> kp stride 162 mod 32 = 2)

typedef float v2f __attribute__((ext_vector_type(2)));

struct W3 { v2f x, y, z; };

__device__ __forceinline__ v2f FMA2(v2f a, v2f b, v2f c) {
    return __builtin_elementwise_fma(a, b, c);
}
__device__ __forceinline__ W3 wsub(W3 a, W3 b) { return {a.x-b.x, a.y-b.y, a.z-b.z}; }
__device__ __forceinline__ W3 wcross(W3 a, W3 b) {
    return { FMA2(a.y, b.z, -(a.z*b.y)),
             FMA2(a.z, b.x, -(a.x*b.z)),
             FMA2(a.x, b.y, -(a.y*b.x)) };
}
__device__ __forceinline__ v2f wdot(W3 a, W3 b) {
    return FMA2(a.x, b.x, FMA2(a.y, b.y, a.z*b.z));
}
// rsq with flush floor: a degenerate face has zero cross -> zero dot numerator,
// so 0 * rsq(FLT_MIN) = 0 reproduces the ref's where(norm>0, ..., 0).
__device__ __forceinline__ v2f rsq_floor(v2f q) {
    q = __builtin_elementwise_max(q, (v2f)(1.17549435e-38f));
    v2f r;
    r.x = __builtin_amdgcn_rsqf(q.x);
    r.y = __builtin_amdgcn_rsqf(q.y);
    return r;
}
__device__ __forceinline__ v2f clamp2(v2f v) {
    v = __builtin_elementwise_max(v, (v2f)(-1.0f + 1e-7f));
    v = __builtin_elementwise_min(v, (v2f)( 1.0f - 1e-7f));
    return v;
}
// asin via Abramowitz-Stegun 4.4.46 (7-term), packed polynomial. |err|<=2e-8.
__device__ __forceinline__ v2f asin2(v2f x) {
    v2f ax; ax.x = fabsf(x.x); ax.y = fabsf(x.y);
    v2f p = FMA2(ax, (v2f)(-0.0012624911f), (v2f)(0.0066700901f));
    p = FMA2(ax, p, (v2f)(-0.0170881256f));
    p = FMA2(ax, p, (v2f)( 0.0308918810f));
    p = FMA2(ax, p, (v2f)(-0.0501743046f));
    p = FMA2(ax, p, (v2f)( 0.0889789874f));
    p = FMA2(ax, p, (v2f)(-0.2145988016f));
    p = FMA2(ax, p, (v2f)( 1.5707963050f));
    v2f om = (v2f)(1.0f) - ax;
    v2f s; s.x = __builtin_amdgcn_sqrtf(om.x); s.y = __builtin_amdgcn_sqrtf(om.y);
    v2f r = FMA2(-s, p, (v2f)(1.57079632679f));
    r.x = copysignf(r.x, x.x);
    r.y = copysignf(r.y, x.y);
    return r;
}

// smem: staging jT1|jT2 = 2*66*18 = 2376 floats; red = 2*16*81 = 2592 floats.
#define SMEM_FLOATS (2 * FPB * RSTRIDE)

__global__ __launch_bounds__(256)
void gli_kernel(const float* __restrict__ m1, const float* __restrict__ m2,
                float* __restrict__ gli)
{
    __shared__ float smem[SMEM_FLOATS];
    float* jT1 = smem;
    float* jT2 = smem + 66 * JSTRIDE;

    const int f0 = blockIdx.x * FPB;
    const int b  = blockIdx.y;
    const int t  = threadIdx.x;

    // Stage FPB frames transposed: jT[off][f] = m[f0+f][off]. Coalesced global.
    const size_t mbase = ((size_t)b * NF + f0) * 66;
    for (int i = t; i < FPB * 66; i += 256) {
        int f   = i / 66;
        int off = i - f * 66;
        jT1[off * JSTRIDE + f] = m1[mbase + i];
        jT2[off * JSTRIDE + f] = m2[mbase + i];
    }
    __syncthreads();

    constexpr int seg_a[16] = {2,5,8,  1,4,7,  3,6,9,12,  14,17,19,  13,16,18};
    constexpr int seg_b[16] = {5,8,11, 4,7,10, 6,9,12,15, 17,19,21,  16,18,20};
    constexpr int seg_p[16] = {0,0,0,  1,1,1,  2,2,2,2,   3,3,3,     4,4,4};

    const int half = t >> 7;         // which 8 i2's this thread owns
    const int kp   = (t >> 4) & 7;   // frame pair: local frames 2kp, 2kp+1
    const int i1   = t & 15;         // motion1 segment (p1 fixed per thread)
    const int fc   = 2 * kp;

    const int a1 = seg_a[i1] * 3, b1 = seg_b[i1] * 3;

    #define LD2(base, off) (*(const v2f*)&(base)[(off) * JSTRIDE + fc])
    W3 S1{LD2(jT1, a1), LD2(jT1, a1+1), LD2(jT1, a1+2)};
    W3 E1{LD2(jT1, b1), LD2(jT1, b1+1), LD2(jT1, b1+2)};
    W3 r12 = wsub(E1, S1);

    v2f acc[5] = {(v2f)(0.0f), (v2f)(0.0f), (v2f)(0.0f), (v2f)(0.0f), (v2f)(0.0f)};

    auto body = [&](int i2) {
        const int a2 = seg_a[i2] * 3, b2 = seg_b[i2] * 3;
        W3 S2{LD2(jT2, a2), LD2(jT2, a2+1), LD2(jT2, a2+2)};
        W3 E2{LD2(jT2, b2), LD2(jT2, b2+1), LD2(jT2, b2+2)};

        W3 r13 = wsub(S2, S1);
        W3 r14 = wsub(E2, S1);
        W3 r23 = wsub(S2, E1);
        W3 r24 = wsub(E2, E1);
        W3 r34 = wsub(E2, S2);

        W3 c0 = wcross(r13, r14);
        W3 c1 = wcross(r14, r24);
        W3 c2 = wcross(r24, r23);
        W3 c3 = wcross(r23, r13);

        v2f n0 = wdot(c0, c0), n1 = wdot(c1, c1);
        v2f n2 = wdot(c2, c2), n3 = wdot(c3, c3);

        v2f i01 = rsq_floor(n0 * n1);
        v2f i12 = rsq_floor(n1 * n2);
        v2f i23 = rsq_floor(n2 * n3);
        v2f i30 = rsq_floor(n3 * n0);

        v2f d0 = clamp2(wdot(c0, c1) * i01);
        v2f d1 = clamp2(wdot(c1, c2) * i12);
        v2f d2 = clamp2(wdot(c2, c3) * i23);
        v2f d3 = clamp2(wdot(c3, c0) * i30);

        v2f g = asin2(d0) + asin2(d1) + asin2(d2) + asin2(d3);

        v2f sgn = wdot(wcross(r34, r12), r13);
        g.x = (sgn.x <= 0.0f) ? -g.x : g.x;
        g.y = (sgn.y <= 0.0f) ? -g.y : g.y;

        acc[seg_p[i2]] += g;   // i2 compile-time after unroll -> folds
    };

    if (half == 0) {           // wave-uniform branch (t>>7)
#pragma unroll
        for (int i2 = 0; i2 < 8; ++i2) body(i2);
    } else {
#pragma unroll
        for (int i2 = 8; i2 < 16; ++i2) body(i2);
    }
    #undef LD2

    __syncthreads();   // staging dead; alias smem as red[2][FPB][RSTRIDE]

    float* red = smem;
#pragma unroll
    for (int p = 0; p < 5; ++p) {
        red[(half * FPB + fc    ) * RSTRIDE + i1 * 5 + p] = acc[p].x * 0.07957747154594767f;
        red[(half * FPB + fc + 1) * RSTRIDE + i1 * 5 + p] = acc[p].y * 0.07957747154594767f;
    }
    __syncthreads();

    // 400 items = FPB frames x 25 bins; sum halves and i1 in path(p1).
    constexpr int grp_s[5] = {0, 3, 6, 10, 13};
    constexpr int grp_e[5] = {3, 6, 10, 13, 16};
    for (int item = t; item < FPB * 25; item += 256) {
        int f   = item / 25;
        int bin = item - f * 25;
        int p1 = bin / 5, p2 = bin - p1 * 5;
        float s = 0.0f;
        for (int i = grp_s[p1]; i < grp_e[p1]; ++i)
            s += red[(f      ) * RSTRIDE + i * 5 + p2]
               + red[(f + FPB) * RSTRIDE + i * 5 + p2];
        gli[((size_t)b * NF + f0 + f) * 25 + bin] = s;
    }
}

// out[b,f] = max_p |gli[b,f+1,p] - gli[b,f,p]|
__global__ __launch_bounds__(256)
void vel_kernel(const float* __restrict__ gli, float* __restrict__ out)
{
    const int f = blockIdx.x * blockDim.x + threadIdx.x;
    const int b = blockIdx.y;
    if (f >= NF - 1) return;

    const float* p0 = gli + ((size_t)b * NF + f) * 25;
    float m = 0.0f;
#pragma unroll
    for (int p = 0; p < 25; ++p)
        m = fmaxf(m, fabsf(p0[p + 25] - p0[p]));
    out[(size_t)b * (NF - 1) + f] = m;
}

extern "C" void kernel_launch(void* const* d_in, const int* in_sizes, int n_in,
                              void* d_out, int out_size, void* d_ws, size_t ws_size,
                              hipStream_t stream)
{
    const float* m1 = (const float*)d_in[0];
    const float* m2 = (const float*)d_in[1];
    float* out = (float*)d_out;
    float* gli = (float*)d_ws;   // 32*1024*25*4 = 3.3 MB

    hipLaunchKernelGGL(gli_kernel, dim3(NF / FPB, NB), dim3(256), 0, stream,
                       m1, m2, gli);
    hipLaunchKernelGGL(vel_kernel, dim3((NF - 1 + 255) / 256, NB), dim3(256),
                       0, stream, gli, out);
}